// Round 14
// baseline (309.336 us; speedup 1.0000x reference)
//
#include <hip/hip_runtime.h>

// SingleLSTM: B=32768, T=28, INPUT=28, HIDDEN=128, LABELS=10, fp32.
// R14 = R13 with 2-tile-group ping-pong: act phases process 8 independent
// element chains (was 4) -> trans pipe (the dominant load: 7 trans/elem at
// ~16 cyc) stays saturated during act; MFMA chain of the NEXT 2-tile group
// (40 MFMAs) is issued first and executes concurrently on the MFMA pipe.
// Registers: acc 2x2x16=64 AGPR + Wh 64 AGPR = 128, arch ~112 -> 240<=256,
// still 2 waves/SIMD, no spill. Structure otherwise R13: 128 rows/block,
// 256 blocks (1/CU, LDS 86KB forces sole residency), one barrier/step,
// early global x loads / late LDS writes, W/bias pre-scaled {-L2E, 2L2E,
// -L2E, -L2E}, c in 2*L2E units (absmax 0.0039 stable R4-R13).

typedef _Float16 f16x8 __attribute__((ext_vector_type(8)));
typedef float f32x4 __attribute__((ext_vector_type(4)));

#define HSTRIDE 136    // f16 elems; 272B row = 17*16B (b128-aligned rows)
#define L2E 1.44269504f

__global__ __launch_bounds__(512, 2)
void lstm_r14(const float* __restrict__ x,      // [B][28][28]
              const float* __restrict__ W,      // [156][512]
              const float* __restrict__ b,      // [512]
              const float* __restrict__ Wfc,    // [128][10]
              const float* __restrict__ bfc,    // [10]
              float* __restrict__ out)          // [B][10]
{
    __shared__ __align__(16) _Float16 h_s[2][128 * HSTRIDE];  // 69632 B
    __shared__ __align__(16) _Float16 xs[2][8 * 512];         // 16384 B

    const int tid  = threadIdx.x;
    const int wave = tid >> 6;
    const int lane = tid & 63;
    const int m16  = lane & 15;
    const int quad = lane >> 4;
    const int rbase = blockIdx.x * 128;
    const int hc = wave * 16 + m16;     // this lane's hidden column

    // ---- zero h buf0 and xs (k>=28 slots must stay 0 forever) ----
    for (int i = tid; i < 128 * HSTRIDE; i += 512) h_s[0][i] = (_Float16)0.0f;
    for (int i = tid; i < 2 * 8 * 512; i += 512) ((_Float16*)xs)[i] = (_Float16)0.0f;

    // ---- W fragments (fp16, pre-scaled), B-layout: lane holds B[k=quad*8+j][col]
    f16x8 Wx[4];        // x rows (k<28, rest 0)
    f16x8 Wh[4][4];     // [ks][gate] -- compiler places in AGPRs
    float bias[4];
    #pragma unroll
    for (int g = 0; g < 4; g++) {
        const int col = g * 128 + wave * 16 + m16;
        const float sc = (g == 1) ? 2.0f * L2E : -L2E;
        bias[g] = sc * (b[col] + (g == 2 ? 1.0f : 0.0f));   // FORGET_BIAS folded
        f16x8 w8;
        #pragma unroll
        for (int j = 0; j < 8; j++) {
            int kk = quad * 8 + j;
            w8[j] = (kk < 28) ? (_Float16)(sc * W[kk * 512 + col]) : (_Float16)0.0f;
        }
        Wx[g] = w8;
        #pragma unroll
        for (int ks = 0; ks < 4; ks++) {
            f16x8 h8;
            #pragma unroll
            for (int j = 0; j < 8; j++)
                h8[j] = (_Float16)(sc * W[(28 + ks * 32 + quad * 8 + j) * 512 + col]);
            Wh[ks][g] = h8;
        }
    }

    // barrier: zero-init must complete before the permuted t=0 staging (R6 race)
    __syncthreads();

    // ---- x staging: 128 rows x 28 k = 3584 = 7 slots x 512 threads ----
    int lsoff[7], goff[7];
    #pragma unroll
    for (int e = 0; e < 7; e++) {
        const int idx = e * 512 + tid;
        const int srow = idx / 28, sk = idx % 28;
        lsoff[e] = (srow >> 4) * 512 + (sk >> 3) * 128 + (srow & 15) * 8 + (sk & 7);
        goff[e]  = (rbase + srow) * 784 + sk;   // fits int
    }

    // stage x for t=0
    #pragma unroll
    for (int e = 0; e < 7; e++) xs[0][lsoff[e]] = (_Float16)x[goff[e]];
    __syncthreads();

    float creg[32];
    #pragma unroll
    for (int i = 0; i < 32; i++) creg[i] = 0.0f;

    const int foff = quad * 128 + m16 * 8;   // A-frag offset inside a chunk

    int buf = 0;
    for (int t = 0; t < 28; t++) {
        const int nb = buf ^ 1;

        // ---- EARLY: issue global loads for t+1 (wait lands at step end) ----
        float xv[7];
        if (t < 27) {
            const float* xt = x + (t + 1) * 28;
            #pragma unroll
            for (int e = 0; e < 7; e++) xv[e] = xt[goff[e]];
        }

        // ---- 4 groups x 2 tiles, group-level MFMA/act ping-pong ----
        f32x4 acc[2][2][4];   // [pingpong][tile-in-group][gate]

        // prologue: group 0 MFMA chains -> acc[0]
        #pragma unroll
        for (int tt = 0; tt < 2; tt++) {
            const int mt = tt;
            f16x8 ax = *(const f16x8*)(&xs[buf][mt * 512 + foff]);
            #pragma unroll
            for (int g = 0; g < 4; g++) {
                acc[0][tt][g] = (f32x4){bias[g], bias[g], bias[g], bias[g]};
                acc[0][tt][g] = __builtin_amdgcn_mfma_f32_16x16x32_f16(ax, Wx[g], acc[0][tt][g], 0, 0, 0);
            }
            #pragma unroll
            for (int ks = 0; ks < 4; ks++) {
                f16x8 ah = *(const f16x8*)(&h_s[buf][(mt * 16 + m16) * HSTRIDE + ks * 32 + quad * 8]);
                #pragma unroll
                for (int g = 0; g < 4; g++)
                    acc[0][tt][g] = __builtin_amdgcn_mfma_f32_16x16x32_f16(ah, Wh[ks][g], acc[0][tt][g], 0, 0, 0);
            }
        }

        #pragma unroll
        for (int grp = 0; grp < 4; grp++) {
            const int cur = grp & 1, nxt = cur ^ 1;

            // issue group grp+1's 40-MFMA chain before act(grp): MFMA pipe
            // runs it while the trans pipe chews act(grp)'s 8 chains
            if (grp < 3) {
                #pragma unroll
                for (int tt = 0; tt < 2; tt++) {
                    const int mt = (grp + 1) * 2 + tt;
                    f16x8 axn = *(const f16x8*)(&xs[buf][mt * 512 + foff]);
                    #pragma unroll
                    for (int g = 0; g < 4; g++) {
                        acc[nxt][tt][g] = (f32x4){bias[g], bias[g], bias[g], bias[g]};
                        acc[nxt][tt][g] = __builtin_amdgcn_mfma_f32_16x16x32_f16(axn, Wx[g], acc[nxt][tt][g], 0, 0, 0);
                    }
                    #pragma unroll
                    for (int ks = 0; ks < 4; ks++) {
                        f16x8 ahn = *(const f16x8*)(&h_s[buf][(mt * 16 + m16) * HSTRIDE + ks * 32 + quad * 8]);
                        #pragma unroll
                        for (int g = 0; g < 4; g++)
                            acc[nxt][tt][g] = __builtin_amdgcn_mfma_f32_16x16x32_f16(ahn, Wh[ks][g], acc[nxt][tt][g], 0, 0, 0);
                    }
                }
            }

            // act for group grp: 2 tiles x 4 r = 8 independent chains
            #pragma unroll
            for (int tt = 0; tt < 2; tt++) {
                const int mt = grp * 2 + tt;
                #pragma unroll
                for (int r = 0; r < 4; r++) {
                    float ei  = __builtin_amdgcn_exp2f(acc[cur][tt][0][r]);   // e^-i
                    float e2j = __builtin_amdgcn_exp2f(acc[cur][tt][1][r]);   // e^2j
                    float ef  = __builtin_amdgcn_exp2f(acc[cur][tt][2][r]);   // e^-(f+1)
                    float eo  = __builtin_amdgcn_exp2f(acc[cur][tt][3][r]);   // e^-o
                    float A   = 1.0f + ei;
                    float Bv  = e2j + 1.0f;
                    float C   = 1.0f + ef;
                    float AB  = A * Bv;
                    float rP  = __builtin_amdgcn_rcpf(AB * C);
                    float num = __builtin_fmaf(e2j, 2.0f * L2E, -2.0f * L2E);
                    float cn  = __builtin_fmaf(creg[mt * 4 + r], AB * rP, num * (C * rP));
                    creg[mt * 4 + r] = cn;
                    float e2c = __builtin_amdgcn_exp2f(cn);                   // e^2c
                    float rQ  = __builtin_amdgcn_rcpf((e2c + 1.0f) * (1.0f + eo));
                    float hv  = (e2c - 1.0f) * rQ;
                    h_s[nb][(mt * 16 + quad * 4 + r) * HSTRIDE + hc] = (_Float16)hv;
                }
            }
        }

        // ---- LATE: stage x(t+1) to LDS (vmcnt satisfied long ago) ----
        if (t < 27) {
            #pragma unroll
            for (int e = 0; e < 7; e++) xs[nb][lsoff[e]] = (_Float16)xv[e];
        }
        __syncthreads();
        buf = nb;
    }

    // ---- FC epilogue: logits = h @ Wfc + bfc (1280 outputs) ----
    for (int i = tid; i < 1280; i += 512) {
        const int row = i / 10, lab = i % 10;
        float acc = bfc[lab];
        #pragma unroll 8
        for (int k = 0; k < 128; k++)
            acc += (float)h_s[buf][row * HSTRIDE + k] * Wfc[k * 10 + lab];
        out[(size_t)(rbase + row) * 10 + lab] = acc;
    }
}

extern "C" void kernel_launch(void* const* d_in, const int* in_sizes, int n_in,
                              void* d_out, int out_size, void* d_ws, size_t ws_size,
                              hipStream_t stream) {
    const float* x   = (const float*)d_in[0];
    const float* W   = (const float*)d_in[1];
    const float* b   = (const float*)d_in[2];
    const float* Wfc = (const float*)d_in[3];
    const float* bfc = (const float*)d_in[4];
    float* out = (float*)d_out;

    const int B = in_sizes[0] / (28 * 28);   // 32768
    const int blocks = B / 128;              // 256 = one per CU
    lstm_r14<<<blocks, 512, 0, stream>>>(x, W, b, Wfc, bfc, out);
}